// Round 3
// baseline (141.249 us; speedup 1.0000x reference)
//
#include <hip/hip_runtime.h>

#define B_SIZE 16384
#define DIM    128
#define NCLS   100
#define NSEG   128
#define SEGSZ  128
#define TS     32
#define MAXTILES 131329
#define PAIR_GRID 1024
#define PREP_GRID 1024

// ---------------- workspace layout (int units) ----------------
#define WS_OFFSETS 0                       // 128
#define WS_SEGHIST 128                     // 100*128, c-major [c*NSEG+g]
#define WS_SEGBASE 12928                   // 100*128, c-major
#define WS_SORTED  25728                   // 16384
#define WS_NORMX   42112                   // 16384 floats (original index order)
#define WS_TILES   58496                   // MAXTILES
#define WS_NTILES  189825
#define WS_DONE    189826
#define WS_PARTIAL 189828                  // PAIR_GRID floats
#define WS_XB      190852                  // 16384*128 bf16 (byte off 763408, 16B aligned)

typedef short bf8 __attribute__((ext_vector_type(8)));
typedef float f32x4 __attribute__((ext_vector_type(4)));

__device__ __forceinline__ unsigned bf16_rne(float f) {
    unsigned u = __float_as_uint(f);
    return (u + 0x7FFFu + ((u >> 16) & 1u)) >> 16;
}

// 1) fp32->bf16 convert + bf16-consistent squared norms (original order) + seg hist
__global__ __launch_bounds__(256) void prep_kernel(
        const float* __restrict__ x, const int* __restrict__ target,
        unsigned short* __restrict__ xb, float* __restrict__ normX,
        int* __restrict__ seg_hist) {
    const int gtid = blockIdx.x * 256 + threadIdx.x;   // 262144 threads
    const int row  = gtid >> 4;
    const int ch   = gtid & 15;

    const float4* src = reinterpret_cast<const float4*>(x + (size_t)row * DIM + ch * 8);
    const float4 v0 = src[0], v1 = src[1];

    unsigned b0 = bf16_rne(v0.x), b1 = bf16_rne(v0.y), b2 = bf16_rne(v0.z), b3 = bf16_rne(v0.w);
    unsigned b4 = bf16_rne(v1.x), b5 = bf16_rne(v1.y), b6 = bf16_rne(v1.z), b7 = bf16_rne(v1.w);
    uint4 o;
    o.x = b0 | (b1 << 16); o.y = b2 | (b3 << 16);
    o.z = b4 | (b5 << 16); o.w = b6 | (b7 << 16);
    reinterpret_cast<uint4*>(xb + (size_t)row * DIM + ch * 8)[0] = o;

    // norm from the ROUNDED values (consistent with bf16 MFMA dots)
    float c0 = __uint_as_float(b0 << 16), c1 = __uint_as_float(b1 << 16);
    float c2 = __uint_as_float(b2 << 16), c3 = __uint_as_float(b3 << 16);
    float c4 = __uint_as_float(b4 << 16), c5 = __uint_as_float(b5 << 16);
    float c6 = __uint_as_float(b6 << 16), c7 = __uint_as_float(b7 << 16);
    float s = c0*c0 + c1*c1 + c2*c2 + c3*c3 + c4*c4 + c5*c5 + c6*c6 + c7*c7;
    #pragma unroll
    for (int off = 1; off < 16; off <<= 1) s += __shfl_xor(s, off, 64);
    if (ch == 0) normX[row] = s;

    // first NSEG blocks also do a per-segment class histogram
    if (blockIdx.x < NSEG) {
        __shared__ int h[NCLS];
        if (threadIdx.x < NCLS) h[threadIdx.x] = 0;
        __syncthreads();
        if (threadIdx.x < SEGSZ)
            atomicAdd(&h[target[blockIdx.x * SEGSZ + threadIdx.x]], 1);
        __syncthreads();
        if (threadIdx.x < NCLS)
            seg_hist[threadIdx.x * NSEG + blockIdx.x] = h[threadIdx.x];
    }
}

// 2) single-block scan: class offsets, per-segment bases, tile list, zero done
__global__ void scan_kernel(const int* __restrict__ seg_hist,
                            int* __restrict__ offsets,
                            int* __restrict__ seg_base,
                            int* __restrict__ tiles,
                            int* __restrict__ ntiles,
                            int* __restrict__ done) {
    __shared__ int tot[NCLS], cls_off[NCLS + 1], tile_off[NCLS + 1];
    const int c = threadIdx.x;
    if (c < NCLS) {
        int s = 0;
        const int4* p = reinterpret_cast<const int4*>(seg_hist + c * NSEG);
        #pragma unroll 8
        for (int g = 0; g < NSEG / 4; ++g) { int4 v = p[g]; s += v.x + v.y + v.z + v.w; }
        tot[c] = s;
    }
    __syncthreads();
    if (c == 0) {
        int a = 0;
        for (int k = 0; k < NCLS; ++k) { cls_off[k] = a; a += tot[k]; }
        cls_off[NCLS] = a;
        *done = 0;
    }
    __syncthreads();
    if (c < NCLS) {
        offsets[c] = cls_off[c];
        int a = cls_off[c];
        for (int g = 0; g < NSEG; ++g) { seg_base[c * NSEG + g] = a; a += seg_hist[c * NSEG + g]; }
        int T = (tot[c] + TS - 1) / TS;
        tot[c] = T * (T + 1) / 2;     // reuse as tile count
    }
    __syncthreads();
    if (c == 0) {
        offsets[NCLS] = cls_off[NCLS];
        int a = 0;
        for (int k = 0; k < NCLS; ++k) { tile_off[k] = a; a += tot[k]; }
        tile_off[NCLS] = a;
        *ntiles = a;
    }
    __syncthreads();
    if (c < NCLS) {
        int o = tile_off[c];
        const int n = cls_off[c + 1] - cls_off[c];
        const int T = (n + TS - 1) / TS;
        for (int ti = 0; ti < T; ++ti)
            for (int tj = ti; tj < T; ++tj)
                tiles[o++] = (c << 18) | (ti << 9) | tj;
    }
}

// 3) stable in-segment rank + scatter (deterministic)
__global__ void scatter_kernel(const int* __restrict__ target,
                               const int* __restrict__ seg_base,
                               int* __restrict__ sorted_idx) {
    __shared__ int tloc[SEGSZ];
    __shared__ int base_s[NCLS];
    const int seg = blockIdx.x;
    const int t = threadIdx.x;
    const int i = seg * SEGSZ + t;
    const int c = target[i];
    tloc[t] = c;
    if (t < NCLS) base_s[t] = seg_base[t * NSEG + seg];
    __syncthreads();
    int r = 0;
    for (int j = 0; j < t; ++j) r += (tloc[j] == c);
    sorted_idx[base_s[c] + r] = i;
}

// 4) MFMA pair kernel: one wave per 32x32 pair tile, fragments straight from L2.
__global__ __launch_bounds__(256) void pair_kernel(
        const unsigned short* __restrict__ xb,
        const int* __restrict__ sorted,
        const int* __restrict__ offsets,
        const float* __restrict__ normX,
        const int* __restrict__ tiles,
        const int* __restrict__ ntiles_p,
        float* __restrict__ partials,
        int* __restrict__ done,
        float* __restrict__ out) {
    const int lane = threadIdx.x & 63;
    const int r16  = lane & 15;    // fragment row within 16
    const int kl   = lane >> 4;    // k-chunk lane 0..3
    const int gwave  = blockIdx.x * 4 + (threadIdx.x >> 6);
    const int nwaves = gridDim.x * 4;
    const int nt = *ntiles_p;

    float acc = 0.0f;

    for (int t = gwave; t < nt; t += nwaves) {
        const int e  = tiles[t];
        const int c  = e >> 18;
        const int ti = (e >> 9) & 511;
        const int tj = e & 511;
        const int beg = offsets[c];
        const int end = offsets[c + 1];
        const int pbase = beg + ti * TS;
        const int qbase = beg + tj * TS;

        const int pa0 = pbase + r16, pa1 = pa0 + 16;
        const int qa0 = qbase + r16, qa1 = qa0 + 16;
        const int ia0 = sorted[pa0 < end ? pa0 : beg];
        const int ia1 = sorted[pa1 < end ? pa1 : beg];
        const int ja0 = sorted[qa0 < end ? qa0 : beg];
        const int ja1 = sorted[qa1 < end ? qa1 : beg];

        const bf8* rA0 = reinterpret_cast<const bf8*>(xb + (size_t)ia0 * DIM) + kl;
        const bf8* rA1 = reinterpret_cast<const bf8*>(xb + (size_t)ia1 * DIM) + kl;
        const bf8* rB0 = reinterpret_cast<const bf8*>(xb + (size_t)ja0 * DIM) + kl;
        const bf8* rB1 = reinterpret_cast<const bf8*>(xb + (size_t)ja1 * DIM) + kl;

        f32x4 c00 = {0.f, 0.f, 0.f, 0.f};
        f32x4 c01 = {0.f, 0.f, 0.f, 0.f};
        f32x4 c10 = {0.f, 0.f, 0.f, 0.f};
        f32x4 c11 = {0.f, 0.f, 0.f, 0.f};
        #pragma unroll
        for (int ks = 0; ks < 4; ++ks) {
            const bf8 a0 = rA0[ks * 4];
            const bf8 a1 = rA1[ks * 4];
            const bf8 b0 = rB0[ks * 4];
            const bf8 b1 = rB1[ks * 4];
            c00 = __builtin_amdgcn_mfma_f32_16x16x32_bf16(a0, b0, c00, 0, 0, 0);
            c01 = __builtin_amdgcn_mfma_f32_16x16x32_bf16(a0, b1, c01, 0, 0, 0);
            c10 = __builtin_amdgcn_mfma_f32_16x16x32_bf16(a1, b0, c10, 0, 0, 0);
            c11 = __builtin_amdgcn_mfma_f32_16x16x32_bf16(a1, b1, c11, 0, 0, 0);
        }

        // epilogue norms: B cols reuse frag-row indices; A rows are (lane>>4)*4+r
        const float nb0 = normX[ja0];
        const float nb1 = normX[ja1];
        float na[8];
        #pragma unroll
        for (int rg = 0; rg < 2; ++rg)
            #pragma unroll
            for (int r = 0; r < 4; ++r) {
                const int pe = pbase + rg * 16 + kl * 4 + r;
                na[rg * 4 + r] = normX[sorted[pe < end ? pe : beg]];
            }

        const bool diag = (ti == tj);
        #pragma unroll
        for (int sub = 0; sub < 4; ++sub) {
            const int rg = sub >> 1, cg = sub & 1;
            const f32x4 cc = (sub == 0) ? c00 : (sub == 1) ? c01 : (sub == 2) ? c10 : c11;
            const int qcol = cg * 16 + r16;
            const int qq = qbase + qcol;
            const float nb = cg ? nb1 : nb0;
            #pragma unroll
            for (int r = 0; r < 4; ++r) {
                const int prow = rg * 16 + kl * 4 + r;
                const int pp = pbase + prow;
                const bool valid = (pp < end) && (qq < end) && (!diag || (prow < qcol));
                if (valid) {
                    const float d2 = na[rg * 4 + r] + nb - 2.0f * cc[r];
                    acc += sqrtf(fmaxf(d2, 0.0f));
                }
            }
        }
    }

    // fixed-order block reduction
    __shared__ float red[256];
    red[threadIdx.x] = acc;
    __syncthreads();
    for (int s = 128; s > 0; s >>= 1) {
        if (threadIdx.x < s) red[threadIdx.x] += red[threadIdx.x + s];
        __syncthreads();
    }
    if (threadIdx.x == 0) partials[blockIdx.x] = red[0];
    __threadfence();
    __shared__ unsigned last;
    if (threadIdx.x == 0) last = (unsigned)atomicAdd(done, 1);
    __syncthreads();
    if (last == gridDim.x - 1) {
        __threadfence();
        float a = 0.0f;
        for (int i = threadIdx.x; i < (int)gridDim.x; i += 256) a += partials[i];
        red[threadIdx.x] = a;
        __syncthreads();
        for (int s = 128; s > 0; s >>= 1) {
            if (threadIdx.x < s) red[threadIdx.x] += red[threadIdx.x + s];
            __syncthreads();
        }
        if (threadIdx.x == 0) out[0] = red[0] / (float)B_SIZE;
    }
}

extern "C" void kernel_launch(void* const* d_in, const int* in_sizes, int n_in,
                              void* d_out, int out_size, void* d_ws, size_t ws_size,
                              hipStream_t stream) {
    const float* x      = (const float*)d_in[0];
    const int*   target = (const int*)d_in[1];
    float*       out    = (float*)d_out;
    int*         ws     = (int*)d_ws;

    int*   offsets  = ws + WS_OFFSETS;
    int*   seg_hist = ws + WS_SEGHIST;
    int*   seg_base = ws + WS_SEGBASE;
    int*   sorted   = ws + WS_SORTED;
    float* normX    = (float*)(ws + WS_NORMX);
    int*   tiles    = ws + WS_TILES;
    int*   ntiles   = ws + WS_NTILES;
    int*   done     = ws + WS_DONE;
    float* partials = (float*)(ws + WS_PARTIAL);
    unsigned short* xb = (unsigned short*)(ws + WS_XB);

    prep_kernel<<<PREP_GRID, 256, 0, stream>>>(x, target, xb, normX, seg_hist);
    scan_kernel<<<1, 128, 0, stream>>>(seg_hist, offsets, seg_base, tiles, ntiles, done);
    scatter_kernel<<<NSEG, SEGSZ, 0, stream>>>(target, seg_base, sorted);
    pair_kernel<<<PAIR_GRID, 256, 0, stream>>>(xb, sorted, offsets, normX,
                                               tiles, ntiles, partials, done, out);
}

// Round 4
// 33.154 us; speedup vs baseline: 4.2604x; 4.2604x over previous
//
#include <hip/hip_runtime.h>

#define B_SIZE 16384
#define DIM    128
#define NCLS   100
#define NSEG   128
#define SEGSZ  128
#define TS     32
#define MAXTILES 131329
#define PAIR_GRID 512

// ---------------- workspace layout (int units) ----------------
#define WS_SEGBASE 0                        // NCLS*NSEG = 12800
#define WS_SORTED  12800                    // 16384
#define WS_NORMS   (12800 + 16384)          // 16384 floats (sorted order)
#define WS_NTILES  (WS_NORMS + 16384)       // 1 (+3 pad)
#define WS_PARTIAL (WS_NTILES + 4)          // 512
#define WS_TILES   (WS_PARTIAL + 512 + 4)   // int2 x MAXTILES (offset even -> 8B aligned)
#define WS_XS      (WS_TILES + 2 * MAXTILES + 2)  // bf16 16384x128, byte offset 16B-aligned

typedef short bf8 __attribute__((ext_vector_type(8)));
typedef float f32x4 __attribute__((ext_vector_type(4)));

__device__ __forceinline__ unsigned bf16_rne(float f) {
    unsigned u = __float_as_uint(f);
    return (u + 0x7FFFu + ((u >> 16) & 1u)) >> 16;
}

// 1) single-block plan: seg-hist (LDS), class offsets, per-segment bases, tile list
__global__ __launch_bounds__(1024) void plan_kernel(const int* __restrict__ target,
                                                    int* __restrict__ seg_base,
                                                    int2* __restrict__ tiles,
                                                    int* __restrict__ ntiles) {
    __shared__ int sh[NSEG * NCLS];          // [g*NCLS + c]
    __shared__ int tot[NCLS], cls_off[NCLS + 1], tile_off[NCLS + 1];
    const int tid = threadIdx.x;
    for (int i = tid; i < NSEG * NCLS; i += 1024) sh[i] = 0;
    __syncthreads();
    for (int i = tid; i < B_SIZE; i += 1024)
        atomicAdd(&sh[(i >> 7) * NCLS + target[i]], 1);
    __syncthreads();
    if (tid < NCLS) {
        int s = 0;
        for (int g = 0; g < NSEG; ++g) s += sh[g * NCLS + tid];
        tot[tid] = s;
    }
    __syncthreads();
    if (tid == 0) {
        int a = 0;
        for (int k = 0; k < NCLS; ++k) { cls_off[k] = a; a += tot[k]; }
        cls_off[NCLS] = a;
    }
    __syncthreads();
    if (tid < NCLS) {
        int a = cls_off[tid];
        for (int g = 0; g < NSEG; ++g) {
            seg_base[tid * NSEG + g] = a;
            a += sh[g * NCLS + tid];
        }
        int T = (tot[tid] + TS - 1) / TS;
        tot[tid] = T * (T + 1) / 2;          // reuse as per-class tile count
    }
    __syncthreads();
    if (tid == 0) {
        int a = 0;
        for (int k = 0; k < NCLS; ++k) { tile_off[k] = a; a += tot[k]; }
        *ntiles = a;
    }
    __syncthreads();
    if (tid < NCLS) {
        const int beg = cls_off[tid], end = cls_off[tid + 1];
        const int T = (end - beg + TS - 1) / TS;
        int o = tile_off[tid];
        const int w0 = (int)((unsigned)beg | ((unsigned)end << 16));
        for (int ti = 0; ti < T; ++ti)
            for (int tj = ti; tj < T; ++tj, ++o)
                tiles[o] = make_int2(w0, ti | (tj << 12));
    }
}

// 2) stable in-segment rank + scatter (deterministic)
__global__ void scatter_kernel(const int* __restrict__ target,
                               const int* __restrict__ seg_base,
                               int* __restrict__ sorted_idx) {
    __shared__ int tloc[SEGSZ];
    __shared__ int base_s[NCLS];
    const int seg = blockIdx.x;
    const int t = threadIdx.x;
    const int i = seg * SEGSZ + t;
    const int c = target[i];
    tloc[t] = c;
    if (t < NCLS) base_s[t] = seg_base[t * NSEG + seg];
    __syncthreads();
    int r = 0;
    for (int j = 0; j < t; ++j) r += (tloc[j] == c);
    sorted_idx[base_s[c] + r] = i;
}

// 3) gather + fp32->bf16 convert in SORTED order + bf16-consistent norms
__global__ __launch_bounds__(256) void gathercvt_kernel(const float* __restrict__ x,
                                                        const int* __restrict__ sorted,
                                                        unsigned short* __restrict__ xs,
                                                        float* __restrict__ normS) {
    const int gtid = blockIdx.x * 256 + threadIdx.x;   // 262144 threads
    const int pos = gtid >> 4;
    const int ch  = gtid & 15;
    const int idx = sorted[pos];

    const float4* src = reinterpret_cast<const float4*>(x + (size_t)idx * DIM + ch * 8);
    const float4 v0 = src[0], v1 = src[1];

    unsigned b0 = bf16_rne(v0.x), b1 = bf16_rne(v0.y), b2 = bf16_rne(v0.z), b3 = bf16_rne(v0.w);
    unsigned b4 = bf16_rne(v1.x), b5 = bf16_rne(v1.y), b6 = bf16_rne(v1.z), b7 = bf16_rne(v1.w);
    uint4 o;
    o.x = b0 | (b1 << 16); o.y = b2 | (b3 << 16);
    o.z = b4 | (b5 << 16); o.w = b6 | (b7 << 16);
    reinterpret_cast<uint4*>(xs + (size_t)pos * DIM + ch * 8)[0] = o;

    float c0 = __uint_as_float(b0 << 16), c1 = __uint_as_float(b1 << 16);
    float c2 = __uint_as_float(b2 << 16), c3 = __uint_as_float(b3 << 16);
    float c4 = __uint_as_float(b4 << 16), c5 = __uint_as_float(b5 << 16);
    float c6 = __uint_as_float(b6 << 16), c7 = __uint_as_float(b7 << 16);
    float s = c0*c0 + c1*c1 + c2*c2 + c3*c3 + c4*c4 + c5*c5 + c6*c6 + c7*c7;
    #pragma unroll
    for (int off = 1; off < 16; off <<= 1) s += __shfl_xor(s, off, 64);
    if (ch == 0) normS[pos] = s;
}

// 4) MFMA pair kernel: one wave per 32x32 tile, contiguous sorted rows, no fences
__global__ __launch_bounds__(256) void pair_kernel(const unsigned short* __restrict__ xs,
                                                   const float* __restrict__ normS,
                                                   const int2* __restrict__ tiles,
                                                   const int* __restrict__ ntiles_p,
                                                   float* __restrict__ partials) {
    const int lane = threadIdx.x & 63;
    const int r16  = lane & 15;
    const int kl   = lane >> 4;
    const int gwave  = blockIdx.x * 4 + (threadIdx.x >> 6);
    const int nwaves = gridDim.x * 4;
    const int nt = *ntiles_p;

    float acc = 0.0f;

    for (int t = gwave; t < nt; t += nwaves) {
        const int2 tw = tiles[t];
        const int beg = tw.x & 0xFFFF;
        const int end = (int)(((unsigned)tw.x) >> 16);
        const int ti  = tw.y & 0xFFF;
        const int tj  = tw.y >> 12;
        const int pbase = beg + ti * TS;
        const int qbase = beg + tj * TS;
        const int last = end - 1;

        const int pa0 = min(pbase + r16, last),      pa1 = min(pbase + 16 + r16, last);
        const int qa0 = min(qbase + r16, last),      qa1 = min(qbase + 16 + r16, last);

        const bf8* rA0 = reinterpret_cast<const bf8*>(xs + (size_t)pa0 * DIM) + kl;
        const bf8* rA1 = reinterpret_cast<const bf8*>(xs + (size_t)pa1 * DIM) + kl;
        const bf8* rB0 = reinterpret_cast<const bf8*>(xs + (size_t)qa0 * DIM) + kl;
        const bf8* rB1 = reinterpret_cast<const bf8*>(xs + (size_t)qa1 * DIM) + kl;

        f32x4 c00 = {0.f, 0.f, 0.f, 0.f};
        f32x4 c01 = {0.f, 0.f, 0.f, 0.f};
        f32x4 c10 = {0.f, 0.f, 0.f, 0.f};
        f32x4 c11 = {0.f, 0.f, 0.f, 0.f};
        #pragma unroll
        for (int ks = 0; ks < 4; ++ks) {
            const bf8 a0 = rA0[ks * 4];
            const bf8 a1 = rA1[ks * 4];
            const bf8 b0 = rB0[ks * 4];
            const bf8 b1 = rB1[ks * 4];
            c00 = __builtin_amdgcn_mfma_f32_16x16x32_bf16(a0, b0, c00, 0, 0, 0);
            c01 = __builtin_amdgcn_mfma_f32_16x16x32_bf16(a0, b1, c01, 0, 0, 0);
            c10 = __builtin_amdgcn_mfma_f32_16x16x32_bf16(a1, b0, c10, 0, 0, 0);
            c11 = __builtin_amdgcn_mfma_f32_16x16x32_bf16(a1, b1, c11, 0, 0, 0);
        }

        const float nb0 = normS[qa0];
        const float nb1 = normS[qa1];
        float na[8];
        #pragma unroll
        for (int rg = 0; rg < 2; ++rg)
            #pragma unroll
            for (int r = 0; r < 4; ++r)
                na[rg * 4 + r] = normS[min(pbase + rg * 16 + kl * 4 + r, last)];

        const bool diag = (ti == tj);
        #pragma unroll
        for (int sub = 0; sub < 4; ++sub) {
            const int rg = sub >> 1, cg = sub & 1;
            const f32x4 cc = (sub == 0) ? c00 : (sub == 1) ? c01 : (sub == 2) ? c10 : c11;
            const int qcol = cg * 16 + r16;
            const int qq = qbase + qcol;
            const float nb = cg ? nb1 : nb0;
            #pragma unroll
            for (int r = 0; r < 4; ++r) {
                const int prow = rg * 16 + kl * 4 + r;
                const int pp = pbase + prow;
                const bool valid = (pp < end) && (qq < end) && (!diag || (prow < qcol));
                if (valid) {
                    const float d2 = na[rg * 4 + r] + nb - 2.0f * cc[r];
                    acc += sqrtf(fmaxf(d2, 0.0f));
                }
            }
        }
    }

    __shared__ float red[256];
    red[threadIdx.x] = acc;
    __syncthreads();
    for (int s = 128; s > 0; s >>= 1) {
        if (threadIdx.x < s) red[threadIdx.x] += red[threadIdx.x + s];
        __syncthreads();
    }
    if (threadIdx.x == 0) partials[blockIdx.x] = red[0];
}

__global__ void reduce_kernel(const float* __restrict__ partials, float* __restrict__ out) {
    __shared__ float sm[256];
    float acc = 0.0f;
    for (int i = threadIdx.x; i < PAIR_GRID; i += 256) acc += partials[i];
    sm[threadIdx.x] = acc;
    __syncthreads();
    for (int s = 128; s > 0; s >>= 1) {
        if (threadIdx.x < s) sm[threadIdx.x] += sm[threadIdx.x + s];
        __syncthreads();
    }
    if (threadIdx.x == 0) out[0] = sm[0] / (float)B_SIZE;
}

extern "C" void kernel_launch(void* const* d_in, const int* in_sizes, int n_in,
                              void* d_out, int out_size, void* d_ws, size_t ws_size,
                              hipStream_t stream) {
    const float* x      = (const float*)d_in[0];
    const int*   target = (const int*)d_in[1];
    float*       out    = (float*)d_out;
    int*         ws     = (int*)d_ws;

    int*   seg_base = ws + WS_SEGBASE;
    int*   sorted   = ws + WS_SORTED;
    float* normS    = (float*)(ws + WS_NORMS);
    int*   ntiles   = ws + WS_NTILES;
    float* partials = (float*)(ws + WS_PARTIAL);
    int2*  tiles    = (int2*)(ws + WS_TILES);
    unsigned short* xs = (unsigned short*)(ws + WS_XS);

    plan_kernel<<<1, 1024, 0, stream>>>(target, seg_base, tiles, ntiles);
    scatter_kernel<<<NSEG, SEGSZ, 0, stream>>>(target, seg_base, sorted);
    gathercvt_kernel<<<1024, 256, 0, stream>>>(x, sorted, xs, normS);
    pair_kernel<<<PAIR_GRID, 256, 0, stream>>>(xs, normS, tiles, ntiles, partials);
    reduce_kernel<<<1, 256, 0, stream>>>(partials, out);
}